// Round 10
// baseline (631.586 us; speedup 1.0000x reference)
//
#include <hip/hip_runtime.h>
#include <hip/hip_bf16.h>

#define DMODEL 1024
#define DINNER 2048
#define DTRANK 64
#define NPROJ  96
#define BATCH  2
#define LIN    2048
#define LOUT   2049
#define MTOT0  4096   // BATCH*LIN
#define MTOT1  4098   // BATCH*LOUT
#define TC     32
#define NCH    65     // ceil(2049/32)

typedef __attribute__((ext_vector_type(8))) short short8;
typedef __attribute__((ext_vector_type(4))) float f32x4;

__device__ __forceinline__ float f_silu(float x)     { return x / (1.f + __expf(-x)); }
__device__ __forceinline__ float f_softplus(float x) { return (x > 20.f) ? x : log1pf(__expf(x)); }
__device__ __forceinline__ short f2b(float x)
{
    __hip_bfloat16 b = __float2bfloat16(x);
    return *reinterpret_cast<short*>(&b);
}
// async global->LDS, 16B per lane; dst = wave-uniform base + lane*16
__device__ __forceinline__ void gload16(const void* g, void* l)
{
    __builtin_amdgcn_global_load_lds(
        (const __attribute__((address_space(1))) void*)g,
        (__attribute__((address_space(3))) void*)l,
        16, 0, 0);
}
// bijective XCD-chunked blockIdx swizzle (8 XCDs): each XCD gets a contiguous
// flat-id chunk so blocks sharing a weight panel co-reside in one L2.
__device__ __forceinline__ void xcd_swizzle(int& bx, int& by)
{
    int nx = gridDim.x;
    int nwg = nx * gridDim.y;
    int f = blockIdx.x + blockIdx.y * nx;
    int xcd = f & 7, i = f >> 3;
    int q = nwg >> 3, r = nwg & 7;
    int w = (xcd < r ? xcd * (q + 1) : r * (q + 1) + (xcd - r) * q) + i;
    bx = w % nx;
    by = w / nx;
}

// ===================== LayerNorm stats (mu, rstd per (b,l)) =====================
__global__ void ln_stats_k(const float* __restrict__ x, float* __restrict__ mu, float* __restrict__ rs)
{
    int b  = blockIdx.y;
    int l0 = blockIdx.x * 64;
    int lc = threadIdx.x & 63;
    int q  = threadIdx.x >> 6;          // 0..3
    const float* xb = x + (size_t)b * DMODEL * LIN + (l0 + lc);
    float s = 0.f, ss = 0.f;
    for (int c = q * 256; c < q * 256 + 256; ++c) {
        float v = xb[(size_t)c * LIN];
        s += v; ss += v * v;
    }
    __shared__ float Ss[4][64];
    __shared__ float Sq[4][64];
    Ss[q][lc] = s; Sq[q][lc] = ss;
    __syncthreads();
    if (threadIdx.x < 64) {
        float st = Ss[0][lc] + Ss[1][lc] + Ss[2][lc] + Ss[3][lc];
        float sq = Sq[0][lc] + Sq[1][lc] + Sq[2][lc] + Sq[3][lc];
        float m = st * (1.f / DMODEL);
        float v = sq * (1.f / DMODEL) - m * m;
        mu[b * LIN + l0 + lc] = m;
        rs[b * LIN + l0 + lc] = 1.f / sqrtf(v + 1e-5f);
    }
}

// ============ LN apply + transpose: x (B,DMODEL,LIN) -> h0T bf16 [m][c] ============
__global__ void lnT_k(const float* __restrict__ x, const float* __restrict__ mu,
                      const float* __restrict__ rs, const float* __restrict__ g,
                      const float* __restrict__ be, short* __restrict__ h0T)
{
    __shared__ float T[32][33];
    int l0 = blockIdx.x * 32;
    int c0 = blockIdx.y * 32;
    int b  = blockIdx.z;
    int tx = threadIdx.x & 31, ty = threadIdx.x >> 5;  // ty 0..7
    const float* xb = x + ((size_t)b * DMODEL + c0) * LIN + l0;
#pragma unroll
    for (int i = 0; i < 4; i++) {
        int cl = ty + 8 * i;
        T[cl][tx] = xb[(size_t)cl * LIN + tx];
    }
    __syncthreads();
    int c = c0 + tx;
    float gg = g[c], bb = be[c];
#pragma unroll
    for (int i = 0; i < 4; i++) {
        int ll = ty + 8 * i;
        int m = b * LIN + l0 + ll;
        float v = (T[tx][ll] - mu[m]) * rs[m] * gg + bb;
        h0T[(size_t)m * DMODEL + c] = f2b(v);
    }
}

// ============ W_dt transpose: [2048][64] fp32 -> WdtT [64][2048] fp32 ============
__global__ void wdtT_k(const float* __restrict__ W_dt, float* __restrict__ WdtT)
{
    __shared__ float T[32][33];
    int n0 = blockIdx.x * 32;   // 64 blocks
    int k0 = blockIdx.y * 32;   // 2 blocks
    int tx = threadIdx.x & 31, ty = threadIdx.x >> 5;  // ty 0..7
#pragma unroll
    for (int i = 0; i < 4; i++) {
        int r = ty + 8 * i;
        T[r][tx] = W_dt[(size_t)(n0 + r) * 64 + k0 + tx];
    }
    __syncthreads();
#pragma unroll
    for (int i = 0; i < 4; i++) {
        int r = ty + 8 * i;
        WdtT[(size_t)(k0 + r) * 2048 + n0 + tx] = T[tx][r];
    }
}

// ===================== single fused fp32 -> bf16 weight conversion =====================
// block ranges (each block = 1024 elements): W_in 1024 | W_inproj 4096 | W_xproj 192 |
// W_outproj 2048 | W_out 1024   (total 8384)
__global__ void cvt_all_k(const float* __restrict__ W_in, const float* __restrict__ W_inproj,
                          const float* __restrict__ W_xproj,
                          const float* __restrict__ W_outproj, const float* __restrict__ W_out,
                          short* __restrict__ Wib, short* __restrict__ Winpb,
                          short* __restrict__ Wxpb,
                          short* __restrict__ Wopb, short* __restrict__ Wob)
{
    int b = blockIdx.x;
    const float* s; short* d; int i;
    if      (b < 1024) { s = W_in;      d = Wib;   i = b; }
    else if (b < 5120) { s = W_inproj;  d = Winpb; i = b - 1024; }
    else if (b < 5312) { s = W_xproj;   d = Wxpb;  i = b - 5120; }
    else if (b < 7360) { s = W_outproj; d = Wopb;  i = b - 5312; }
    else               { s = W_out;     d = Wob;   i = b - 7360; }
    int idx = (i * 256 + threadIdx.x) * 4;
    float4 v = *(const float4*)(s + idx);
    d[idx + 0] = f2b(v.x); d[idx + 1] = f2b(v.y);
    d[idx + 2] = f2b(v.z); d[idx + 3] = f2b(v.w);
}

// ===================== bf16 MFMA GEMM: C[m][n] = sum_k A[m][k] * W[n][k] =====================
// global_load_lds staging (width 16), linear LDS [128][32] bf16, XCD-chunked swizzle,
// LDS-staged epilogue (full-line coalesced writes; no write-allocate fetch).
// EPI: 0 plain fp32 C | 1 +bias fp32 | 4 bf16-only into Cb | 5 swapped-scatter (+bias[m])
template<int EPI>
__global__ __launch_bounds__(256) void gemm_bf(
    const short* __restrict__ A, int lda,
    const short* __restrict__ W, int ldb,
    float* __restrict__ C, int ldc,
    short* __restrict__ Cb, int ldcb,
    int M, int N, int K,
    const float* __restrict__ bias)
{
    __shared__ char LDSall[16896];          // As(8KB) + Bs(8KB) | ctile 32x132 fp32
    short* As = (short*)LDSall;
    short* Bs = (short*)(LDSall + 8192);

    int tid  = threadIdx.x;
    int lane = tid & 63, wid = tid >> 6;
    int wr = wid >> 1, wc = wid & 1;          // wave quadrant (2x2 of 64x64)
    int fr = lane & 15, kg = lane >> 4;       // fragment row + k-group
    int bx, by;
    xcd_swizzle(bx, by);
    int m0 = bx * 128, n0 = by * 128;

    // staging map: round r in {0,1}: row = (wid*2+r)*16 + lane/4, col = (lane&3)*8 elems
    int scol  = (lane & 3) * 8;
    int srow0 = wid * 32 + (lane >> 2);
    int srow1 = srow0 + 16;
    const short* a0 = A + (size_t)(m0 + srow0) * lda + scol;
    const short* a1 = A + (size_t)(m0 + srow1) * lda + scol;
    const short* b0 = W + (size_t)(n0 + srow0) * ldb + scol;
    const short* b1 = W + (size_t)(n0 + srow1) * ldb + scol;
    char* asd0 = LDSall + (wid * 2 + 0) * 1024;
    char* asd1 = LDSall + (wid * 2 + 1) * 1024;
    char* bsd0 = LDSall + 8192 + (wid * 2 + 0) * 1024;
    char* bsd1 = LDSall + 8192 + (wid * 2 + 1) * 1024;

    f32x4 acc[4][4];
#pragma unroll
    for (int mi = 0; mi < 4; mi++)
#pragma unroll
        for (int ni = 0; ni < 4; ni++) acc[mi][ni] = (f32x4){0.f, 0.f, 0.f, 0.f};

    for (int k0 = 0; k0 < K; k0 += 32) {
        gload16(a0 + k0, asd0);
        gload16(a1 + k0, asd1);
        gload16(b0 + k0, bsd0);
        gload16(b1 + k0, bsd1);
        __syncthreads();

        short8 af[4], bf[4];
#pragma unroll
        for (int mi = 0; mi < 4; mi++)
            af[mi] = *(const short8*)&As[(wr * 64 + mi * 16 + fr) * 32 + kg * 8];
#pragma unroll
        for (int ni = 0; ni < 4; ni++)
            bf[ni] = *(const short8*)&Bs[(wc * 64 + ni * 16 + fr) * 32 + kg * 8];
#pragma unroll
        for (int mi = 0; mi < 4; mi++)
#pragma unroll
            for (int ni = 0; ni < 4; ni++)
                acc[mi][ni] = __builtin_amdgcn_mfma_f32_16x16x32_bf16(
                    af[mi], bf[ni], acc[mi][ni], 0, 0, 0);
        __syncthreads();
    }

    // ---- LDS-staged epilogue: 4 passes of 32 rows x 128 cols ----
    float* ctile = (float*)LDSall;            // stride 132 floats
    int row = tid >> 3;                       // 0..31
    int cs  = (tid & 7) * 16;                 // col start
#pragma unroll
    for (int p = 0; p < 4; p++) {
        __syncthreads();
#pragma unroll
        for (int ni = 0; ni < 4; ni++)
#pragma unroll
            for (int r = 0; r < 4; r++)
                ctile[(wr * 16 + kg * 4 + r) * 132 + wc * 64 + ni * 16 + fr] = acc[p][ni][r];
        __syncthreads();
        int mrow = m0 + ((row < 16) ? (p * 16 + row) : (64 + p * 16 + (row - 16)));
        int n = n0 + cs;
        if (mrow >= M || n >= N) continue;
        const float* src = &ctile[row * 132 + cs];
        if (EPI == 5) {
            float bv = bias[mrow];
            if (n + 15 < N && !(n < LOUT && n + 15 >= LOUT)) {
                int bq = (n >= LOUT) ? 1 : 0;
                float* dst = C + ((size_t)bq * DMODEL + mrow) * LOUT + (n - bq * LOUT);
#pragma unroll
                for (int e = 0; e < 4; e++) {
                    f32x4 v = *(const f32x4*)(src + 4 * e);
                    v += bv;
                    *(f32x4*)(dst + 4 * e) = v;
                }
            } else {
                for (int j = 0; j < 16; j++) {
                    int nj = n + j;
                    if (nj < N) {
                        int bq = (nj >= LOUT) ? 1 : 0;
                        C[((size_t)bq * DMODEL + mrow) * LOUT + (nj - bq * LOUT)] = src[j] + bv;
                    }
                }
            }
        } else if (EPI == 4) {
            short8 o0, o1;
#pragma unroll
            for (int e = 0; e < 8; e++) { o0[e] = f2b(src[e]); o1[e] = f2b(src[8 + e]); }
            *(short8*)&Cb[(size_t)mrow * ldcb + n]     = o0;
            *(short8*)&Cb[(size_t)mrow * ldcb + n + 8] = o1;
        } else {
#pragma unroll
            for (int e = 0; e < 4; e++) {
                f32x4 v = *(const f32x4*)(src + 4 * e);
                if (EPI == 1) v += *(const f32x4*)&bias[n + 4 * e];
                *(f32x4*)&C[(size_t)mrow * ldc + n + 4 * e] = v;
            }
        }
    }
}

// ============ fused dt kernel v2: dt[m][n] = softplus(xdbl[m][0:64] . WdtT[:, n] + b_dt[n]) ============
__global__ __launch_bounds__(256) void dtfuse2_k(const float* __restrict__ xdbl,
                                                 const float* __restrict__ WdtT,
                                                 const float* __restrict__ b_dt,
                                                 float* __restrict__ dtout)
{
    int t  = threadIdx.x;
    int m0 = blockIdx.x * 8;
    __shared__ float dr[8][64];
    {
        int k = t & 63, r = t >> 6;             // r 0..3
        int ma = m0 + r, mb = m0 + r + 4;
        dr[r][k]     = (ma < MTOT1) ? xdbl[(size_t)ma * NPROJ + k] : 0.f;
        dr[r + 4][k] = (mb < MTOT1) ? xdbl[(size_t)mb * NPROJ + k] : 0.f;
    }
    __syncthreads();

    int n0 = t * 4;
    f32x4 acc0[8], acc1[8];
#pragma unroll
    for (int mi = 0; mi < 8; mi++) {
        acc0[mi] = (f32x4){0.f, 0.f, 0.f, 0.f};
        acc1[mi] = (f32x4){0.f, 0.f, 0.f, 0.f};
    }

    for (int k = 0; k < 64; k += 4) {
        f32x4 w0[4], w1[4];
#pragma unroll
        for (int e = 0; e < 4; e++) {
            w0[e] = *(const f32x4*)&WdtT[(size_t)(k + e) * 2048 + n0];
            w1[e] = *(const f32x4*)&WdtT[(size_t)(k + e) * 2048 + n0 + 1024];
        }
#pragma unroll
        for (int mi = 0; mi < 8; mi++) {
            f32x4 d = *(const f32x4*)&dr[mi][k];
#pragma unroll
            for (int e = 0; e < 4; e++) {
                acc0[mi] += d[e] * w0[e];
                acc1[mi] += d[e] * w1[e];
            }
        }
    }

    f32x4 b0 = *(const f32x4*)&b_dt[n0];
    f32x4 b1 = *(const f32x4*)&b_dt[n0 + 1024];
#pragma unroll
    for (int mi = 0; mi < 8; mi++) {
        int m = m0 + mi;
        if (m >= MTOT1) continue;
        f32x4 v0, v1;
#pragma unroll
        for (int e = 0; e < 4; e++) {
            v0[e] = f_softplus(acc0[mi][e] + b0[e]);
            v1[e] = f_softplus(acc1[mi][e] + b1[e]);
        }
        *(f32x4*)&dtout[(size_t)m * DINNER + n0]        = v0;
        *(f32x4*)&dtout[(size_t)m * DINNER + n0 + 1024] = v1;
    }
}

// ===================== depthwise convs (position-major, lanes = feature) =====================
__global__ void conv1_k(const float* __restrict__ h1, const float* __restrict__ cw,
                        const float* __restrict__ cb, short* __restrict__ h2b)
{
    int c = blockIdx.x * 256 + threadIdx.x;     // 0..1023
    int m = blockIdx.y;                         // 0..4097
    int b = (m >= LOUT) ? 1 : 0;
    int l = m - b * LOUT;
    float4 wv = ((const float4*)cw)[c];
    const float* w = (const float*)&wv;
    float acc = cb[c];
#pragma unroll
    for (int k = 0; k < 4; k++) {
        int li = l - 2 + k;
        if (li >= 0 && li < LIN)
            acc += h1[((size_t)b * LIN + li) * DMODEL + c] * w[k];
    }
    h2b[(size_t)m * DMODEL + c] = f2b(f_silu(acc));
}

__global__ void conv2_k(const float* __restrict__ xz, const float* __restrict__ cw,
                        const float* __restrict__ cb, float* __restrict__ u,
                        short* __restrict__ ub)
{
    int d = blockIdx.x * 256 + threadIdx.x;     // 0..2047
    int m = blockIdx.y;
    int b = (m >= LOUT) ? 1 : 0;
    int l = m - b * LOUT;
    float4 wv = ((const float4*)cw)[d];
    const float* w = (const float*)&wv;
    float acc = cb[d];
#pragma unroll
    for (int k = 0; k < 4; k++) {
        int li = l - 3 + k;                     // causal pad(3,0)
        if (li >= 0)
            acc += xz[((size_t)b * LOUT + li) * (2 * DINNER) + d] * w[k];
    }
    float s = f_silu(acc);
    u [(size_t)m * DINNER + d] = s;
    ub[(size_t)m * DINNER + d] = f2b(s);
}

// ===================== chunked selective scan (position-major) =====================
__global__ void scan1_k(const float* __restrict__ dt, const float* __restrict__ u,
                        const float* __restrict__ xdbl, const float* __restrict__ A_log,
                        float* __restrict__ sP, float* __restrict__ sH)
{
    int d = blockIdx.x * 256 + threadIdx.x;
    int c = blockIdx.y;
    int b = blockIdx.z;
    int t0 = c * TC;
    int tlen = LOUT - t0; if (tlen > TC) tlen = TC;

    float Ad[16], h[16], P[16];
#pragma unroll
    for (int q = 0; q < 4; q++) {
        float4 av = ((const float4*)A_log)[d * 4 + q];
        Ad[q*4+0] = -__expf(av.x); Ad[q*4+1] = -__expf(av.y);
        Ad[q*4+2] = -__expf(av.z); Ad[q*4+3] = -__expf(av.w);
    }
#pragma unroll
    for (int s = 0; s < 16; s++) { h[s] = 0.f; P[s] = 1.f; }

    size_t row0 = (size_t)b * LOUT + t0;
    const float* dtp = dt + row0 * DINNER + d;
    const float* up  = u  + row0 * DINNER + d;
    const float* Bp  = xdbl + row0 * NPROJ + DTRANK;
    for (int t = 0; t < tlen; t++) {
        float dtt = dtp[(size_t)t * DINNER];
        float du  = dtt * up[(size_t)t * DINNER];
        const float* Bt = Bp + (size_t)t * NPROJ;
#pragma unroll
        for (int s = 0; s < 16; s++) {
            float a = __expf(dtt * Ad[s]);
            h[s] = a * h[s] + du * Bt[s];
            P[s] *= a;
        }
    }
    size_t base = ((size_t)(b * NCH + c) * 16) * DINNER + d;
#pragma unroll
    for (int s = 0; s < 16; s++) {
        sP[base + (size_t)s * DINNER] = P[s];
        sH[base + (size_t)s * DINNER] = h[s];
    }
}

__global__ void scan2_k(const float* __restrict__ sP, float* __restrict__ sH)
{
    int gid = blockIdx.x * 256 + threadIdx.x;   // B*16*DINNER = 65536
    int d = gid & (DINNER - 1);
    int s = (gid >> 11) & 15;
    int b = gid >> 15;
    size_t base = ((size_t)(b * NCH) * 16 + s) * DINNER + d;
    const size_t cstep = (size_t)16 * DINNER;
    float hrun = 0.f;
    for (int c = 0; c < NCH; c++) {
        size_t idx = base + (size_t)c * cstep;
        float Pv = sP[idx], hl = sH[idx];
        sH[idx] = hrun;
        hrun = Pv * hrun + hl;
    }
}

__global__ void scan3_k(const float* __restrict__ dt, const float* __restrict__ u,
                        const float* __restrict__ xdbl, const float* __restrict__ A_log,
                        const float* __restrict__ Dp, const float* __restrict__ xz,
                        const float* __restrict__ sH, short* __restrict__ ymb)
{
    int d = blockIdx.x * 256 + threadIdx.x;
    int c = blockIdx.y;
    int b = blockIdx.z;
    int t0 = c * TC;
    int tlen = LOUT - t0; if (tlen > TC) tlen = TC;

    float Ad[16], h[16];
#pragma unroll
    for (int q = 0; q < 4; q++) {
        float4 av = ((const float4*)A_log)[d * 4 + q];
        Ad[q*4+0] = -__expf(av.x); Ad[q*4+1] = -__expf(av.y);
        Ad[q*4+2] = -__expf(av.z); Ad[q*4+3] = -__expf(av.w);
    }
    size_t sbase = ((size_t)(b * NCH + c) * 16) * DINNER + d;
#pragma unroll
    for (int s = 0; s < 16; s++) h[s] = sH[sbase + (size_t)s * DINNER];

    float Dpd = Dp[d];
    size_t row0 = (size_t)b * LOUT + t0;
    const float* dtp = dt + row0 * DINNER + d;
    const float* up  = u  + row0 * DINNER + d;
    const float* Bp  = xdbl + row0 * NPROJ + DTRANK;
    const float* Cp  = Bp + 16;
    const float* zp  = xz + row0 * (2 * DINNER) + DINNER + d;
    short* yp = ymb + row0 * DINNER + d;
    for (int t = 0; t < tlen; t++) {
        float dtt = dtp[(size_t)t * DINNER];
        float ut  = up[(size_t)t * DINNER];
        float du  = dtt * ut;
        const float* Bt = Bp + (size_t)t * NPROJ;
        const float* Ct = Cp + (size_t)t * NPROJ;
        float y = 0.f;
#pragma unroll
        for (int s = 0; s < 16; s++) {
            float a = __expf(dtt * Ad[s]);
            h[s] = a * h[s] + du * Bt[s];
            y += h[s] * Ct[s];
        }
        float z = zp[(size_t)t * (2 * DINNER)];
        yp[(size_t)t * DINNER] = f2b((y + ut * Dpd) * f_silu(z));
    }
}

// ===================== launcher =====================
extern "C" void kernel_launch(void* const* d_in, const int* in_sizes, int n_in,
                              void* d_out, int out_size, void* d_ws, size_t ws_size,
                              hipStream_t stream)
{
    (void)in_sizes; (void)n_in; (void)out_size; (void)ws_size;
    const float* x        = (const float*)d_in[0];
    const float* ln_g     = (const float*)d_in[1];
    const float* ln_b     = (const float*)d_in[2];
    const float* W_in     = (const float*)d_in[3];
    const float* b_in     = (const float*)d_in[4];
    const float* conv_w   = (const float*)d_in[5];
    const float* conv_b   = (const float*)d_in[6];
    const float* W_inproj = (const float*)d_in[7];
    const float* m_conv_w = (const float*)d_in[8];
    const float* m_conv_b = (const float*)d_in[9];
    const float* W_xproj  = (const float*)d_in[10];
    const float* W_dt     = (const float*)d_in[11];
    const float* b_dt     = (const float*)d_in[12];
    const float* A_log    = (const float*)d_in[13];
    const float* Dp       = (const float*)d_in[14];
    const float* W_outproj= (const float*)d_in[15];
    const float* W_out    = (const float*)d_in[16];
    const float* b_out    = (const float*)d_in[17];
    float* out = (float*)d_out;

    // ---- fp32 region ----
    float* F    = (float*)d_ws;
    float* mu   = F;                                    //      4096
    float* rs   = F + 4096;                             //      4096
    float* h1   = F + 8192;                             // 4096*1024
    float* xz   = h1 + (size_t)MTOT0 * DMODEL;          // 4098*4096
    float* uu   = xz + (size_t)MTOT1 * 2 * DINNER;      // 4098*2048
    float* xdbl = uu + (size_t)MTOT1 * DINNER;          // 4098*96
    float* dt   = xdbl + (size_t)MTOT1 * NPROJ;         // 4098*2048
    float* sP   = dt + (size_t)MTOT1 * DINNER;          // 2*65*16*2048
    float* sH   = sP + (size_t)BATCH * NCH * 16 * DINNER;
    float* WdtT = sH + (size_t)BATCH * NCH * 16 * DINNER;  // 64*2048 fp32
    float* fend = WdtT + (size_t)DTRANK * DINNER;

    // ---- bf16 region ----
    short* S     = (short*)fend;
    short* h0T   = S;                                   // 4096*1024
    short* h2b   = h0T + (size_t)MTOT0 * DMODEL;        // 4098*1024
    short* ub    = h2b + (size_t)MTOT1 * DMODEL;        // 4098*2048
    short* Wib   = ub  + (size_t)MTOT1 * DINNER;        // 1024*1024
    short* Winpb = Wib   + (size_t)DMODEL * DMODEL;     // 4096*1024
    short* Wxpb  = Winpb + (size_t)(2*DINNER) * DMODEL; // 96*2048
    short* Wopb  = Wxpb  + (size_t)NPROJ * DINNER;      // 1024*2048
    short* Wob   = Wopb  + (size_t)DMODEL * DINNER;     // 1024*1024
    // aliases (lifetime-disjoint):
    short* ymb   = ub;             // ymb [4098][2048]; ub dead after xproj-GEMM
    short* o1b   = (short*)h1;     // o1b [4098][1024]; h1 dead after conv1 (16.8MB region)

    // 0) weight conversions + dt-weight fp32 transpose
    cvt_all_k<<<8384, 256, 0, stream>>>(W_in, W_inproj, W_xproj, W_outproj, W_out,
                                        Wib, Winpb, Wxpb, Wopb, Wob);
    wdtT_k<<<dim3(64, 2), 256, 0, stream>>>(W_dt, WdtT);
    // 1) LN stats + LN-apply/transpose -> h0T bf16 [m][c]
    ln_stats_k<<<dim3(32, 2), 256, 0, stream>>>(x, mu, rs);
    lnT_k<<<dim3(64, 32, 2), 256, 0, stream>>>(x, mu, rs, ln_g, ln_b, h0T);
    // 2) h1 = h0T @ W_in^T + b_in                  (4096 x 1024) fp32
    gemm_bf<1><<<dim3(32, 8), 256, 0, stream>>>(h0T, DMODEL, Wib, DMODEL,
        h1, DMODEL, nullptr, 0, MTOT0, DMODEL, DMODEL, b_in);
    // 3) h2b = bf16(silu(dwconv(h1, pad(2,2))))    (4098 x 1024)
    conv1_k<<<dim3(4, MTOT1), 256, 0, stream>>>(h1, conv_w, conv_b, h2b);
    // 4) xz = h2b @ W_inproj^T                     (4098 x 4096) fp32
    gemm_bf<0><<<dim3(33, 32), 256, 0, stream>>>(h2b, DMODEL, Winpb, DMODEL,
        xz, 2 * DINNER, nullptr, 0, MTOT1, 2 * DINNER, DMODEL, nullptr);
    // 5) u/ub = silu(causal dwconv(xi))            (4098 x 2048)
    conv2_k<<<dim3(8, MTOT1), 256, 0, stream>>>(xz, m_conv_w, m_conv_b, uu, ub);
    // 6) xdbl = ub @ W_xproj^T                     (4098 x 96) fp32
    gemm_bf<0><<<dim3(33, 1), 256, 0, stream>>>(ub, DINNER, Wxpb, DINNER,
        xdbl, NPROJ, nullptr, 0, MTOT1, NPROJ, DINNER, nullptr);
    // 7) dt = softplus(xdbl[:, :64] @ W_dt^T + b_dt)  (4098 x 2048)
    dtfuse2_k<<<513, 256, 0, stream>>>(xdbl, WdtT, b_dt, dt);
    // 8-10) chunked scan -> ymb = bf16((y + u*Dp)*silu(z))
    scan1_k<<<dim3(8, NCH, 2), 256, 0, stream>>>(dt, uu, xdbl, A_log, sP, sH);
    scan2_k<<<dim3(256), 256, 0, stream>>>(sP, sH);
    scan3_k<<<dim3(8, NCH, 2), 256, 0, stream>>>(dt, uu, xdbl, A_log, Dp, xz, sH, ymb);
    // 11) o1b = bf16(ymb @ W_outproj^T)            (4098 x 1024)
    gemm_bf<4><<<dim3(33, 8), 256, 0, stream>>>(ymb, DINNER, Wopb, DINNER,
        nullptr, 0, o1b, DMODEL, MTOT1, DMODEL, DINNER, nullptr);
    // 12) out = o1b @ W_out^T + b_out, operand-swapped scatter to (B, DMODEL, LOUT)
    gemm_bf<5><<<dim3(8, 33), 256, 0, stream>>>(Wob, DMODEL, o1b, DMODEL,
        out, 0, nullptr, 0, DMODEL, MTOT1, DMODEL, b_out);
}

// Round 12
// 557.721 us; speedup vs baseline: 1.1324x; 1.1324x over previous
//
#include <hip/hip_runtime.h>
#include <hip/hip_bf16.h>

#define DMODEL 1024
#define DINNER 2048
#define DTRANK 64
#define NPROJ  96
#define BATCH  2
#define LIN    2048
#define LOUT   2049
#define MTOT0  4096   // BATCH*LIN
#define MTOT1  4098   // BATCH*LOUT
#define TC     64
#define NCH    33     // ceil(2049/64)

typedef __attribute__((ext_vector_type(8))) short short8;
typedef __attribute__((ext_vector_type(4))) float f32x4;

__device__ __forceinline__ float f_silu(float x)     { return x / (1.f + __expf(-x)); }
__device__ __forceinline__ float f_softplus(float x) { return (x > 20.f) ? x : log1pf(__expf(x)); }
__device__ __forceinline__ short f2b(float x)
{
    __hip_bfloat16 b = __float2bfloat16(x);
    return *reinterpret_cast<short*>(&b);
}
// async global->LDS, 16B per lane; dst = wave-uniform base + lane*16
__device__ __forceinline__ void gload16(const void* g, void* l)
{
    __builtin_amdgcn_global_load_lds(
        (const __attribute__((address_space(1))) void*)g,
        (__attribute__((address_space(3))) void*)l,
        16, 0, 0);
}
// bijective XCD-chunked blockIdx swizzle (8 XCDs)
__device__ __forceinline__ void xcd_swizzle(int& bx, int& by)
{
    int nx = gridDim.x;
    int nwg = nx * gridDim.y;
    int f = blockIdx.x + blockIdx.y * nx;
    int xcd = f & 7, i = f >> 3;
    int q = nwg >> 3, r = nwg & 7;
    int w = (xcd < r ? xcd * (q + 1) : r * (q + 1) + (xcd - r) * q) + i;
    bx = w % nx;
    by = w / nx;
}

// ===================== LayerNorm stats (mu, rstd per (b,l)) =====================
__global__ void ln_stats_k(const float* __restrict__ x, float* __restrict__ mu, float* __restrict__ rs)
{
    int b  = blockIdx.y;
    int l0 = blockIdx.x * 64;
    int lc = threadIdx.x & 63;
    int q  = threadIdx.x >> 6;          // 0..3
    const float* xb = x + (size_t)b * DMODEL * LIN + (l0 + lc);
    float s = 0.f, ss = 0.f;
    for (int c = q * 256; c < q * 256 + 256; ++c) {
        float v = xb[(size_t)c * LIN];
        s += v; ss += v * v;
    }
    __shared__ float Ss[4][64];
    __shared__ float Sq[4][64];
    Ss[q][lc] = s; Sq[q][lc] = ss;
    __syncthreads();
    if (threadIdx.x < 64) {
        float st = Ss[0][lc] + Ss[1][lc] + Ss[2][lc] + Ss[3][lc];
        float sq = Sq[0][lc] + Sq[1][lc] + Sq[2][lc] + Sq[3][lc];
        float m = st * (1.f / DMODEL);
        float v = sq * (1.f / DMODEL) - m * m;
        mu[b * LIN + l0 + lc] = m;
        rs[b * LIN + l0 + lc] = 1.f / sqrtf(v + 1e-5f);
    }
}

// ============ LN apply + transpose: x (B,DMODEL,LIN) -> h0T bf16 [m][c] ============
__global__ void lnT_k(const float* __restrict__ x, const float* __restrict__ mu,
                      const float* __restrict__ rs, const float* __restrict__ g,
                      const float* __restrict__ be, short* __restrict__ h0T)
{
    __shared__ float T[32][33];
    int l0 = blockIdx.x * 32;
    int c0 = blockIdx.y * 32;
    int b  = blockIdx.z;
    int tx = threadIdx.x & 31, ty = threadIdx.x >> 5;  // ty 0..7
    const float* xb = x + ((size_t)b * DMODEL + c0) * LIN + l0;
#pragma unroll
    for (int i = 0; i < 4; i++) {
        int cl = ty + 8 * i;
        T[cl][tx] = xb[(size_t)cl * LIN + tx];
    }
    __syncthreads();
    int c = c0 + tx;
    float gg = g[c], bb = be[c];
#pragma unroll
    for (int i = 0; i < 4; i++) {
        int ll = ty + 8 * i;
        int m = b * LIN + l0 + ll;
        float v = (T[tx][ll] - mu[m]) * rs[m] * gg + bb;
        h0T[(size_t)m * DMODEL + c] = f2b(v);
    }
}

// ===================== single fused fp32 -> bf16 weight conversion =====================
// block ranges (each block = 1024 elements): W_in 1024 | W_inproj 4096 | W_xproj 192 |
// W_dt 128 | W_outproj 2048 | W_out 1024   (total 8512)
__global__ void cvt_all_k(const float* __restrict__ W_in, const float* __restrict__ W_inproj,
                          const float* __restrict__ W_xproj, const float* __restrict__ W_dt,
                          const float* __restrict__ W_outproj, const float* __restrict__ W_out,
                          short* __restrict__ Wib, short* __restrict__ Winpb,
                          short* __restrict__ Wxpb, short* __restrict__ Wdtb,
                          short* __restrict__ Wopb, short* __restrict__ Wob)
{
    int b = blockIdx.x;
    const float* s; short* d; int i;
    if      (b < 1024) { s = W_in;      d = Wib;   i = b; }
    else if (b < 5120) { s = W_inproj;  d = Winpb; i = b - 1024; }
    else if (b < 5312) { s = W_xproj;   d = Wxpb;  i = b - 5120; }
    else if (b < 5440) { s = W_dt;      d = Wdtb;  i = b - 5312; }
    else if (b < 7488) { s = W_outproj; d = Wopb;  i = b - 5440; }
    else               { s = W_out;     d = Wob;   i = b - 7488; }
    int idx = (i * 256 + threadIdx.x) * 4;
    float4 v = *(const float4*)(s + idx);
    d[idx + 0] = f2b(v.x); d[idx + 1] = f2b(v.y);
    d[idx + 2] = f2b(v.z); d[idx + 3] = f2b(v.w);
}

// ===================== bf16 MFMA GEMM: C[m][n] = sum_k A[m][k] * W[n][k] =====================
// global_load_lds staging (width 16), linear LDS [128][32] bf16, XCD-chunked swizzle,
// LDS-staged epilogue (full-line coalesced writes; no write-allocate fetch).
// EPI: 0 plain fp32 | 1 +bias fp32 | 2 softplus(+bias) fp32 | 3 fp32 + bf16 copy (n<64) into Cb
//      4 bf16-only into Cb | 5 swapped-scatter (+bias[m]) to (B,DMODEL,LOUT)
template<int EPI>
__global__ __launch_bounds__(256) void gemm_bf(
    const short* __restrict__ A, int lda,
    const short* __restrict__ W, int ldb,
    float* __restrict__ C, int ldc,
    short* __restrict__ Cb, int ldcb,
    int M, int N, int K,
    const float* __restrict__ bias)
{
    __shared__ char LDSall[16896];          // As(8KB) + Bs(8KB) | ctile 32x132 fp32
    short* As = (short*)LDSall;
    short* Bs = (short*)(LDSall + 8192);

    int tid  = threadIdx.x;
    int lane = tid & 63, wid = tid >> 6;
    int wr = wid >> 1, wc = wid & 1;          // wave quadrant (2x2 of 64x64)
    int fr = lane & 15, kg = lane >> 4;       // fragment row + k-group
    int bx, by;
    xcd_swizzle(bx, by);
    int m0 = bx * 128, n0 = by * 128;

    // staging map: round r in {0,1}: row = (wid*2+r)*16 + lane/4, col = (lane&3)*8 elems
    int scol  = (lane & 3) * 8;
    int srow0 = wid * 32 + (lane >> 2);
    int srow1 = srow0 + 16;
    const short* a0 = A + (size_t)(m0 + srow0) * lda + scol;
    const short* a1 = A + (size_t)(m0 + srow1) * lda + scol;
    const short* b0 = W + (size_t)(n0 + srow0) * ldb + scol;
    const short* b1 = W + (size_t)(n0 + srow1) * ldb + scol;
    char* asd0 = LDSall + (wid * 2 + 0) * 1024;
    char* asd1 = LDSall + (wid * 2 + 1) * 1024;
    char* bsd0 = LDSall + 8192 + (wid * 2 + 0) * 1024;
    char* bsd1 = LDSall + 8192 + (wid * 2 + 1) * 1024;

    f32x4 acc[4][4];
#pragma unroll
    for (int mi = 0; mi < 4; mi++)
#pragma unroll
        for (int ni = 0; ni < 4; ni++) acc[mi][ni] = (f32x4){0.f, 0.f, 0.f, 0.f};

    for (int k0 = 0; k0 < K; k0 += 32) {
        gload16(a0 + k0, asd0);
        gload16(a1 + k0, asd1);
        gload16(b0 + k0, bsd0);
        gload16(b1 + k0, bsd1);
        __syncthreads();

        short8 af[4], bf[4];
#pragma unroll
        for (int mi = 0; mi < 4; mi++)
            af[mi] = *(const short8*)&As[(wr * 64 + mi * 16 + fr) * 32 + kg * 8];
#pragma unroll
        for (int ni = 0; ni < 4; ni++)
            bf[ni] = *(const short8*)&Bs[(wc * 64 + ni * 16 + fr) * 32 + kg * 8];
#pragma unroll
        for (int mi = 0; mi < 4; mi++)
#pragma unroll
            for (int ni = 0; ni < 4; ni++)
                acc[mi][ni] = __builtin_amdgcn_mfma_f32_16x16x32_bf16(
                    af[mi], bf[ni], acc[mi][ni], 0, 0, 0);
        __syncthreads();
    }

    // ---- LDS-staged epilogue: 4 passes of 32 rows x 128 cols ----
    float* ctile = (float*)LDSall;            // stride 132 floats
    int row = tid >> 3;                       // 0..31
    int cs  = (tid & 7) * 16;                 // col start
#pragma unroll
    for (int p = 0; p < 4; p++) {
        __syncthreads();
#pragma unroll
        for (int ni = 0; ni < 4; ni++)
#pragma unroll
            for (int r = 0; r < 4; r++)
                ctile[(wr * 16 + kg * 4 + r) * 132 + wc * 64 + ni * 16 + fr] = acc[p][ni][r];
        __syncthreads();
        int mrow = m0 + ((row < 16) ? (p * 16 + row) : (64 + p * 16 + (row - 16)));
        int n = n0 + cs;
        if (mrow >= M || n >= N) continue;
        const float* src = &ctile[row * 132 + cs];
        if (EPI == 5) {
            float bv = bias[mrow];
            if (n + 15 < N && !(n < LOUT && n + 15 >= LOUT)) {
                int bq = (n >= LOUT) ? 1 : 0;
                float* dst = C + ((size_t)bq * DMODEL + mrow) * LOUT + (n - bq * LOUT);
#pragma unroll
                for (int e = 0; e < 4; e++) {
                    f32x4 v = *(const f32x4*)(src + 4 * e);
                    v += bv;
                    *(f32x4*)(dst + 4 * e) = v;
                }
            } else {
                for (int j = 0; j < 16; j++) {
                    int nj = n + j;
                    if (nj < N) {
                        int bq = (nj >= LOUT) ? 1 : 0;
                        C[((size_t)bq * DMODEL + mrow) * LOUT + (nj - bq * LOUT)] = src[j] + bv;
                    }
                }
            }
        } else if (EPI == 4) {
            short8 o0, o1;
#pragma unroll
            for (int e = 0; e < 8; e++) { o0[e] = f2b(src[e]); o1[e] = f2b(src[8 + e]); }
            *(short8*)&Cb[(size_t)mrow * ldcb + n]     = o0;
            *(short8*)&Cb[(size_t)mrow * ldcb + n + 8] = o1;
        } else {
#pragma unroll
            for (int e = 0; e < 4; e++) {
                f32x4 v = *(const f32x4*)(src + 4 * e);
                if (EPI == 1) v += *(const f32x4*)&bias[n + 4 * e];
                if (EPI == 2) {
                    f32x4 bb = *(const f32x4*)&bias[n + 4 * e];
#pragma unroll
                    for (int j = 0; j < 4; j++) v[j] = f_softplus(v[j] + bb[j]);
                }
                *(f32x4*)&C[(size_t)mrow * ldc + n + 4 * e] = v;
            }
            if (EPI == 3 && n < DTRANK) {
                short8 o0, o1;
#pragma unroll
                for (int e = 0; e < 8; e++) { o0[e] = f2b(src[e]); o1[e] = f2b(src[8 + e]); }
                *(short8*)&Cb[(size_t)mrow * ldcb + n]     = o0;
                *(short8*)&Cb[(size_t)mrow * ldcb + n + 8] = o1;
            }
        }
    }
}

// ===================== depthwise convs (position-major, lanes = feature) =====================
__global__ void conv1_k(const float* __restrict__ h1, const float* __restrict__ cw,
                        const float* __restrict__ cb, short* __restrict__ h2b)
{
    int c = blockIdx.x * 256 + threadIdx.x;     // 0..1023
    int m = blockIdx.y;                         // 0..4097
    int b = (m >= LOUT) ? 1 : 0;
    int l = m - b * LOUT;
    float4 wv = ((const float4*)cw)[c];
    const float* w = (const float*)&wv;
    float acc = cb[c];
#pragma unroll
    for (int k = 0; k < 4; k++) {
        int li = l - 2 + k;
        if (li >= 0 && li < LIN)
            acc += h1[((size_t)b * LIN + li) * DMODEL + c] * w[k];
    }
    h2b[(size_t)m * DMODEL + c] = f2b(f_silu(acc));
}

__global__ void conv2_k(const float* __restrict__ xz, const float* __restrict__ cw,
                        const float* __restrict__ cb, float* __restrict__ u,
                        short* __restrict__ ub)
{
    int d = blockIdx.x * 256 + threadIdx.x;     // 0..2047
    int m = blockIdx.y;
    int b = (m >= LOUT) ? 1 : 0;
    int l = m - b * LOUT;
    float4 wv = ((const float4*)cw)[d];
    const float* w = (const float*)&wv;
    float acc = cb[d];
#pragma unroll
    for (int k = 0; k < 4; k++) {
        int li = l - 3 + k;                     // causal pad(3,0)
        if (li >= 0)
            acc += xz[((size_t)b * LOUT + li) * (2 * DINNER) + d] * w[k];
    }
    float s = f_silu(acc);
    u [(size_t)m * DINNER + d] = s;
    ub[(size_t)m * DINNER + d] = f2b(s);
}

// ===================== chunked selective scan (position-major) =====================
__global__ void scan1_k(const float* __restrict__ dt, const float* __restrict__ u,
                        const float* __restrict__ xdbl, const float* __restrict__ A_log,
                        float* __restrict__ sP, float* __restrict__ sH)
{
    int d = blockIdx.x * 256 + threadIdx.x;
    int c = blockIdx.y;
    int b = blockIdx.z;
    int t0 = c * TC;
    int tlen = LOUT - t0; if (tlen > TC) tlen = TC;

    float Ad[16], h[16], P[16];
#pragma unroll
    for (int q = 0; q < 4; q++) {
        float4 av = ((const float4*)A_log)[d * 4 + q];
        Ad[q*4+0] = -__expf(av.x); Ad[q*4+1] = -__expf(av.y);
        Ad[q*4+2] = -__expf(av.z); Ad[q*4+3] = -__expf(av.w);
    }
#pragma unroll
    for (int s = 0; s < 16; s++) { h[s] = 0.f; P[s] = 1.f; }

    size_t row0 = (size_t)b * LOUT + t0;
    const float* dtp = dt + row0 * DINNER + d;
    const float* up  = u  + row0 * DINNER + d;
    const float* Bp  = xdbl + row0 * NPROJ + DTRANK;
    for (int t = 0; t < tlen; t++) {
        float dtt = dtp[(size_t)t * DINNER];
        float du  = dtt * up[(size_t)t * DINNER];
        const float* Bt = Bp + (size_t)t * NPROJ;
#pragma unroll
        for (int s = 0; s < 16; s++) {
            float a = __expf(dtt * Ad[s]);
            h[s] = a * h[s] + du * Bt[s];
            P[s] *= a;
        }
    }
    size_t base = ((size_t)(b * NCH + c) * 16) * DINNER + d;
#pragma unroll
    for (int s = 0; s < 16; s++) {
        sP[base + (size_t)s * DINNER] = P[s];
        sH[base + (size_t)s * DINNER] = h[s];
    }
}

__global__ void scan2_k(const float* __restrict__ sP, float* __restrict__ sH)
{
    int gid = blockIdx.x * 256 + threadIdx.x;   // B*16*DINNER = 65536
    int d = gid & (DINNER - 1);
    int s = (gid >> 11) & 15;
    int b = gid >> 15;
    size_t base = ((size_t)(b * NCH) * 16 + s) * DINNER + d;
    const size_t cstep = (size_t)16 * DINNER;
    float hrun = 0.f;
    for (int c = 0; c < NCH; c++) {
        size_t idx = base + (size_t)c * cstep;
        float Pv = sP[idx], hl = sH[idx];
        sH[idx] = hrun;
        hrun = Pv * hrun + hl;
    }
}

__global__ void scan3_k(const float* __restrict__ dt, const float* __restrict__ u,
                        const float* __restrict__ xdbl, const float* __restrict__ A_log,
                        const float* __restrict__ Dp, const float* __restrict__ xz,
                        const float* __restrict__ sH, short* __restrict__ ymb)
{
    int d = blockIdx.x * 256 + threadIdx.x;
    int c = blockIdx.y;
    int b = blockIdx.z;
    int t0 = c * TC;
    int tlen = LOUT - t0; if (tlen > TC) tlen = TC;

    float Ad[16], h[16];
#pragma unroll
    for (int q = 0; q < 4; q++) {
        float4 av = ((const float4*)A_log)[d * 4 + q];
        Ad[q*4+0] = -__expf(av.x); Ad[q*4+1] = -__expf(av.y);
        Ad[q*4+2] = -__expf(av.z); Ad[q*4+3] = -__expf(av.w);
    }
    size_t sbase = ((size_t)(b * NCH + c) * 16) * DINNER + d;
#pragma unroll
    for (int s = 0; s < 16; s++) h[s] = sH[sbase + (size_t)s * DINNER];

    float Dpd = Dp[d];
    size_t row0 = (size_t)b * LOUT + t0;
    const float* dtp = dt + row0 * DINNER + d;
    const float* up  = u  + row0 * DINNER + d;
    const float* Bp  = xdbl + row0 * NPROJ + DTRANK;
    const float* Cp  = Bp + 16;
    const float* zp  = xz + row0 * (2 * DINNER) + DINNER + d;
    short* yp = ymb + row0 * DINNER + d;
    for (int t = 0; t < tlen; t++) {
        float dtt = dtp[(size_t)t * DINNER];
        float ut  = up[(size_t)t * DINNER];
        float du  = dtt * ut;
        const float* Bt = Bp + (size_t)t * NPROJ;
        const float* Ct = Cp + (size_t)t * NPROJ;
        float y = 0.f;
#pragma unroll
        for (int s = 0; s < 16; s++) {
            float a = __expf(dtt * Ad[s]);
            h[s] = a * h[s] + du * Bt[s];
            y += h[s] * Ct[s];
        }
        float z = zp[(size_t)t * (2 * DINNER)];
        yp[(size_t)t * DINNER] = f2b((y + ut * Dpd) * f_silu(z));
    }
}

// ===================== launcher =====================
extern "C" void kernel_launch(void* const* d_in, const int* in_sizes, int n_in,
                              void* d_out, int out_size, void* d_ws, size_t ws_size,
                              hipStream_t stream)
{
    (void)in_sizes; (void)n_in; (void)out_size; (void)ws_size;
    const float* x        = (const float*)d_in[0];
    const float* ln_g     = (const float*)d_in[1];
    const float* ln_b     = (const float*)d_in[2];
    const float* W_in     = (const float*)d_in[3];
    const float* b_in     = (const float*)d_in[4];
    const float* conv_w   = (const float*)d_in[5];
    const float* conv_b   = (const float*)d_in[6];
    const float* W_inproj = (const float*)d_in[7];
    const float* m_conv_w = (const float*)d_in[8];
    const float* m_conv_b = (const float*)d_in[9];
    const float* W_xproj  = (const float*)d_in[10];
    const float* W_dt     = (const float*)d_in[11];
    const float* b_dt     = (const float*)d_in[12];
    const float* A_log    = (const float*)d_in[13];
    const float* Dp       = (const float*)d_in[14];
    const float* W_outproj= (const float*)d_in[15];
    const float* W_out    = (const float*)d_in[16];
    const float* b_out    = (const float*)d_in[17];
    float* out = (float*)d_out;

    // ---- fp32 region ----
    float* F    = (float*)d_ws;
    float* mu   = F;                                    //      4096
    float* rs   = F + 4096;                             //      4096
    float* h1   = F + 8192;                             // 4096*1024
    float* xz   = h1 + (size_t)MTOT0 * DMODEL;          // 4098*4096
    float* uu   = xz + (size_t)MTOT1 * 2 * DINNER;      // 4098*2048
    float* xdbl = uu + (size_t)MTOT1 * DINNER;          // 4098*96
    float* dt   = xdbl + (size_t)MTOT1 * NPROJ;         // 4098*2048
    float* sP   = dt + (size_t)MTOT1 * DINNER;          // 2*33*16*2048
    float* sH   = sP + (size_t)BATCH * NCH * 16 * DINNER;
    float* fend = sH + (size_t)BATCH * NCH * 16 * DINNER;

    // ---- bf16 region ----
    short* S     = (short*)fend;
    short* h0T   = S;                                   // 4096*1024
    short* h2b   = h0T + (size_t)MTOT0 * DMODEL;        // 4098*1024
    short* ub    = h2b + (size_t)MTOT1 * DMODEL;        // 4098*2048
    short* Wib   = ub  + (size_t)MTOT1 * DINNER;        // 1024*1024
    short* Winpb = Wib   + (size_t)DMODEL * DMODEL;     // 4096*1024
    short* Wxpb  = Winpb + (size_t)(2*DINNER) * DMODEL; // 96*2048
    short* Wdtb  = Wxpb  + (size_t)NPROJ * DINNER;      // 2048*64
    short* Wopb  = Wdtb  + (size_t)DINNER * DTRANK;     // 1024*2048
    short* Wob   = Wopb  + (size_t)DMODEL * DINNER;     // 1024*1024
    // aliases (lifetime-disjoint):
    short* dtin  = h0T;            // dtin [4098][64]; h0T dead after h1-GEMM
    short* ymb   = ub;             // ymb [4098][2048]; ub dead after xproj-GEMM
    short* o1b   = (short*)h1;     // o1b [4098][1024]; h1 dead after conv1

    // 0) all weight conversions to bf16 (one kernel)
    cvt_all_k<<<8512, 256, 0, stream>>>(W_in, W_inproj, W_xproj, W_dt, W_outproj, W_out,
                                        Wib, Winpb, Wxpb, Wdtb, Wopb, Wob);
    // 1) LN stats + LN-apply/transpose -> h0T bf16 [m][c]
    ln_stats_k<<<dim3(32, 2), 256, 0, stream>>>(x, mu, rs);
    lnT_k<<<dim3(64, 32, 2), 256, 0, stream>>>(x, mu, rs, ln_g, ln_b, h0T);
    // 2) h1 = h0T @ W_in^T + b_in                  (4096 x 1024) fp32
    gemm_bf<1><<<dim3(32, 8), 256, 0, stream>>>(h0T, DMODEL, Wib, DMODEL,
        h1, DMODEL, nullptr, 0, MTOT0, DMODEL, DMODEL, b_in);
    // 3) h2b = bf16(silu(dwconv(h1, pad(2,2))))    (4098 x 1024)
    conv1_k<<<dim3(4, MTOT1), 256, 0, stream>>>(h1, conv_w, conv_b, h2b);
    // 4) xz = h2b @ W_inproj^T                     (4098 x 4096) fp32
    gemm_bf<0><<<dim3(33, 32), 256, 0, stream>>>(h2b, DMODEL, Winpb, DMODEL,
        xz, 2 * DINNER, nullptr, 0, MTOT1, 2 * DINNER, DMODEL, nullptr);
    // 5) u/ub = silu(causal dwconv(xi))            (4098 x 2048)
    conv2_k<<<dim3(8, MTOT1), 256, 0, stream>>>(xz, m_conv_w, m_conv_b, uu, ub);
    // 6) xdbl = ub @ W_xproj^T (+ bf16 dtin copy)  (4098 x 96) fp32
    gemm_bf<3><<<dim3(33, 1), 256, 0, stream>>>(ub, DINNER, Wxpb, DINNER,
        xdbl, NPROJ, dtin, DTRANK, MTOT1, NPROJ, DINNER, nullptr);
    // 7) dt = softplus(dtin @ W_dt^T + b_dt)       (4098 x 2048), K=64 MFMA + coalesced epi
    gemm_bf<2><<<dim3(33, 16), 256, 0, stream>>>(dtin, DTRANK, Wdtb, DTRANK,
        dt, DINNER, nullptr, 0, MTOT1, DINNER, DTRANK, b_dt);
    // 8-10) chunked scan -> ymb = bf16((y + u*Dp)*silu(z))
    scan1_k<<<dim3(8, NCH, 2), 256, 0, stream>>>(dt, uu, xdbl, A_log, sP, sH);
    scan2_k<<<dim3(256), 256, 0, stream>>>(sP, sH);
    scan3_k<<<dim3(8, NCH, 2), 256, 0, stream>>>(dt, uu, xdbl, A_log, Dp, xz, sH, ymb);
    // 11) o1b = bf16(ymb @ W_outproj^T)            (4098 x 1024)
    gemm_bf<4><<<dim3(33, 8), 256, 0, stream>>>(ymb, DINNER, Wopb, DINNER,
        nullptr, 0, o1b, DMODEL, MTOT1, DMODEL, DINNER, nullptr);
    // 12) out = o1b @ W_out^T + b_out, operand-swapped scatter to (B, DMODEL, LOUT)
    gemm_bf<5><<<dim3(8, 33), 256, 0, stream>>>(Wob, DMODEL, o1b, DMODEL,
        out, 0, nullptr, 0, DMODEL, MTOT1, DMODEL, b_out);
}